// Round 11
// baseline (259.649 us; speedup 1.0000x reference)
//
#include <hip/hip_runtime.h>
#include <hip/hip_bf16.h>

typedef __hip_bfloat16 bf16;
typedef __attribute__((ext_vector_type(8))) short short8;
typedef __attribute__((ext_vector_type(4))) float f32x4;
typedef __attribute__((ext_vector_type(16))) float f32x16;
#define MFMA16(a, b, c) __builtin_amdgcn_mfma_f32_16x16x32_bf16(a, b, c, 0, 0, 0)
#define MFMA32(a, b, c) __builtin_amdgcn_mfma_f32_32x32x16_bf16(a, b, c, 0, 0, 0)

#define BB   16
#define CCH  512
#define NN   1024
#define LLT  77
#define LPAD 128
#define NHH  8
#define HDD  64
#define GGN  32
#define NKV  1101   /* 1024 + 77 */
#define KVP  1152   /* 18 * 64, padded KV rows */
#define QSC  0.18033688f  /* 0.125 * log2(e) */

__device__ __forceinline__ unsigned short f2bu(float f){
  bf16 h = __float2bfloat16(f);
  return *reinterpret_cast<unsigned short*>(&h);
}

// single-instruction packed f32->bf16 (RNE)
__device__ __forceinline__ unsigned pk2(float lo, float hi){
  unsigned r;
  asm("v_cvt_pk_bf16_f32 %0, %1, %2" : "=v"(r) : "v"(lo), "v"(hi));
  return r;
}

// raw v_exp_f32 (exp2)
__device__ __forceinline__ float fexp2(float x){
  float r;
  asm("v_exp_f32 %0, %1" : "=v"(r) : "v"(x));
  return r;
}

// v_permlane32_swap_b32: new_a = {a.lo, b.lo}, new_b = {a.hi, b.hi}
__device__ __forceinline__ void pl32swap(unsigned &a, unsigned &b){
  asm("v_permlane32_swap_b32 %0, %1" : "+v"(a), "+v"(b));
}

// async global->LDS DMA, 16B per lane: lds dest = uniform base + lane*16,
// global src is per-lane.
__device__ __forceinline__ void gload16(const bf16* g, bf16* l){
  __builtin_amdgcn_global_load_lds(
      (const __attribute__((address_space(1))) unsigned int*)g,
      (__attribute__((address_space(3))) unsigned int*)l,
      16, 0, 0);
}

// ---- fused GroupNorm (stats + normalize, two-pass per (b,g) block) + weight
// prep. img: blocks 0-511, text: 512-1023, weights: 1024-1407.
// A (b,g) slice is 64KB (img) / 5KB (text): pass 1 reduces to m,r; the slice
// stays L2-hot so pass 2's re-read costs no second HBM fetch. Replaces the
// old gn_stats + norm_all pair (x was read twice from HBM).
__global__ __launch_bounds__(256) void gn_norm_kernel(
    const float* __restrict__ x, const float* __restrict__ t,
    const float* __restrict__ gqs, const float* __restrict__ gqb,
    const float* __restrict__ gks, const float* __restrict__ gkb,
    const float* __restrict__ gts, const float* __restrict__ gtb,
    const float* __restrict__ W0, const float* __restrict__ W1,
    const float* __restrict__ W2, const float* __restrict__ W3,
    const float* __restrict__ W4, const float* __restrict__ W5,
    bf16* __restrict__ Wt,
    bf16* __restrict__ Xq, bf16* __restrict__ Xkv, bf16* __restrict__ Tn)
{
  __shared__ float sh1[256], sh2[256], mr[2];
  __shared__ alignas(16) float Ws[64][68];
  const int tid = threadIdx.x;
  const int bid = blockIdx.x;

  if (bid < 512){
    // ------------------------------ img GN: stats + Xq/Xkv writes
    const int b = bid >> 5, g = bid & 31;
    const float* xb = x + (size_t)b * NN * CCH + g * 16;
    float s = 0.f, s2 = 0.f;
    for (int i = tid; i < 4096; i += 256){
      const int n = i >> 2, cq = (i & 3) * 4;
      float4 v = *(const float4*)(xb + (size_t)n * CCH + cq);
      s  += v.x + v.y + v.z + v.w;
      s2 += v.x * v.x + v.y * v.y + v.z * v.z + v.w * v.w;
    }
    sh1[tid] = s; sh2[tid] = s2;
    __syncthreads();
    for (int off = 128; off > 0; off >>= 1){
      if (tid < off){ sh1[tid] += sh1[tid + off]; sh2[tid] += sh2[tid + off]; }
      __syncthreads();
    }
    if (tid == 0){
      const float inv = 1.f / 16384.f;
      const float m = sh1[0] * inv;
      mr[0] = m;
      mr[1] = rsqrtf(sh2[0] * inv - m * m + 1e-6f);
    }
    __syncthreads();
    const float m = mr[0], r = mr[1];
    const int ch0 = g * 16;
    for (int i = tid; i < 4096; i += 256){
      const int n = i >> 2, cq = (i & 3) * 4;
      const int ch = ch0 + cq;
      float4 v  = *(const float4*)(xb + (size_t)n * CCH + cq);  // L2-hot
      float4 sq = *(const float4*)(gqs + ch), bq = *(const float4*)(gqb + ch);
      float4 sk = *(const float4*)(gks + ch), bk = *(const float4*)(gkb + ch);
      const float n0 = (v.x - m) * r, n1 = (v.y - m) * r;
      const float n2 = (v.z - m) * r, n3 = (v.w - m) * r;
      uint2 oq, ok;
      oq.x = pk2((n0 * sq.x + bq.x) * QSC, (n1 * sq.y + bq.y) * QSC);
      oq.y = pk2((n2 * sq.z + bq.z) * QSC, (n3 * sq.w + bq.w) * QSC);
      ok.x = pk2(n0 * sk.x + bk.x, n1 * sk.y + bk.y);
      ok.y = pk2(n2 * sk.z + bk.z, n3 * sk.w + bk.w);
      const size_t off = ((size_t)b * NN + n) * CCH + ch;
      *(uint2*)(Xq  + off) = oq;
      *(uint2*)(Xkv + off) = ok;
    }
  } else if (bid < 1024){
    // ------------------------------ text GN: stats + Tn writes (pad to 128)
    const int b = (bid - 512) >> 5, g = (bid - 512) & 31;
    const float* tb = t + (size_t)b * LLT * CCH + g * 16;
    float s = 0.f, s2 = 0.f;
    for (int i = tid; i < 308; i += 256){  // 77 rows x 4 chunks
      const int l = i >> 2, cq = (i & 3) * 4;
      float4 v = *(const float4*)(tb + (size_t)l * CCH + cq);
      s  += v.x + v.y + v.z + v.w;
      s2 += v.x * v.x + v.y * v.y + v.z * v.z + v.w * v.w;
    }
    sh1[tid] = s; sh2[tid] = s2;
    __syncthreads();
    for (int off = 128; off > 0; off >>= 1){
      if (tid < off){ sh1[tid] += sh1[tid + off]; sh2[tid] += sh2[tid + off]; }
      __syncthreads();
    }
    if (tid == 0){
      const float inv = 1.f / (float)(LLT * 16);
      const float m = sh1[0] * inv;
      mr[0] = m;
      mr[1] = rsqrtf(sh2[0] * inv - m * m + 1e-6f);
    }
    __syncthreads();
    const float m = mr[0], r = mr[1];
    const int ch0 = g * 16;
    for (int i = tid; i < 512; i += 256){  // 128 rows x 4 chunks
      const int l = i >> 2, cq = (i & 3) * 4;
      const int ch = ch0 + cq;
      uint2 o;
      if (l < LLT){
        float4 v  = *(const float4*)(tb + (size_t)l * CCH + cq);
        float4 sv = *(const float4*)(gts + ch), bv = *(const float4*)(gtb + ch);
        o.x = pk2((v.x - m) * r * sv.x + bv.x, (v.y - m) * r * sv.y + bv.y);
        o.y = pk2((v.z - m) * r * sv.z + bv.z, (v.w - m) * r * sv.w + bv.w);
      } else {
        o.x = 0u; o.y = 0u;
      }
      *(uint2*)(Tn + ((size_t)b * LPAD + l) * CCH + ch) = o;
    }
  } else {
    // ------------------------------ weight prep (unchanged math)
    const int i = bid - 1024;            // 0..383
    const int wsel = i >> 6;             // 0..5
    const int rem  = i & 63;
    const int n0 = (rem & 7) * 64, k0 = (rem >> 3) * 64;
    const float* W = wsel == 0 ? W0 : wsel == 1 ? W1 : wsel == 2 ? W2 :
                     wsel == 3 ? W3 : wsel == 4 ? W4 : W5;
    bf16* dst = Wt + (size_t)wsel * CCH * CCH;

    const int rr = tid >> 2, c = (tid & 3) * 16;
    const float* src = W + (size_t)(k0 + rr) * CCH + n0 + c;
    *(float4*)&Ws[rr][c]      = *(const float4*)(src);
    *(float4*)&Ws[rr][c + 4]  = *(const float4*)(src + 4);
    *(float4*)&Ws[rr][c + 8]  = *(const float4*)(src + 8);
    *(float4*)&Ws[rr][c + 12] = *(const float4*)(src + 12);
    __syncthreads();

    const int nr = tid >> 2, kc = (tid & 3) * 16;
    uint4 o0, o1;
    o0.x = pk2(Ws[kc + 0][nr],  Ws[kc + 1][nr]);
    o0.y = pk2(Ws[kc + 2][nr],  Ws[kc + 3][nr]);
    o0.z = pk2(Ws[kc + 4][nr],  Ws[kc + 5][nr]);
    o0.w = pk2(Ws[kc + 6][nr],  Ws[kc + 7][nr]);
    o1.x = pk2(Ws[kc + 8][nr],  Ws[kc + 9][nr]);
    o1.y = pk2(Ws[kc + 10][nr], Ws[kc + 11][nr]);
    o1.z = pk2(Ws[kc + 12][nr], Ws[kc + 13][nr]);
    o1.w = pk2(Ws[kc + 14][nr], Ws[kc + 15][nr]);
    bf16* d = dst + (size_t)(n0 + nr) * CCH + k0 + kc;
    *(uint4*)d = o0;
    *(uint4*)(d + 8) = o1;
  }
}

// -------- fused projections: self QKV (blocks 0-1535) + cross KV (1536-1791) -
// Self: 128x128-tile GEMM with prefetch pipeline: double-buffered LDS,
// gload_lds for tile kt+1 issued into buf^1 BEFORE the ds_read+MFMA of tile
// kt, ONE barrier per K-step. (UNCHANGED from round 10)
__global__ __launch_bounds__(256) void proj_all_mfma(
    const bf16* __restrict__ Xq, const bf16* __restrict__ Xkv,
    const bf16* __restrict__ Tn, const bf16* __restrict__ Wt,
    bf16* __restrict__ Qo, bf16* __restrict__ Ko, bf16* __restrict__ Vo)
{
  __shared__ alignas(16) char SHRAW[65536];
  const int tid  = threadIdx.x;
  const int wave = tid >> 6, lane = tid & 63;
  const int l16 = lane & 15, quad = lane >> 4;
  const int bx = blockIdx.x;

  if (bx < 1536){
    bf16 (*T)[4][64][64] = reinterpret_cast<bf16(*)[4][64][64]>(SHRAW);
    const int wr = wave >> 1, wc = wave & 1;
    const int ct = bx >> 7;             // 0..11
    const int rt = bx & 127;            // 0..127
    const int mat = ct >> 2;            // 0=Q, 1=K, 2=V
    const int cm0 = (ct & 3) * 128;
    const int b  = rt >> 3;
    const int n0 = (rt & 7) * 128;

    const bf16* A  = (mat == 0) ? Xq : Xkv;
    const bf16* Bw = Wt + (size_t)mat * CCH * CCH + (size_t)cm0 * CCH;

    f32x4 acc[4][4];
    #pragma unroll
    for (int rf = 0; rf < 4; rf++)
      #pragma unroll
      for (int cf = 0; cf < 4; cf++) acc[rf][cf] = (f32x4){0.f,0.f,0.f,0.f};

    const int lrow = lane >> 3, lcol = (lane & 7) * 8;
    const bf16* srcbase = (wave < 2)
        ? A  + ((size_t)b * NN + n0 + wave * 64) * CCH
        : Bw + (size_t)((wave - 2) * 64) * CCH;

    #pragma unroll
    for (int c = 0; c < 8; c++)
      gload16(srcbase + (size_t)(c * 8 + lrow) * CCH + lcol, &T[0][wave][c * 8][0]);
    __syncthreads();

    int cur = 0;
    for (int kt = 0; kt < 8; kt++){
      if (kt < 7){
        const int kc = (kt + 1) * 64;
        #pragma unroll
        for (int c = 0; c < 8; c++)
          gload16(srcbase + (size_t)(c * 8 + lrow) * CCH + kc + lcol,
                  &T[cur ^ 1][wave][c * 8][0]);
      }

      short8 af[4][2];
      #pragma unroll
      for (int rf = 0; rf < 4; rf++){
        af[rf][0] = *(const short8*)&T[cur][wr][rf * 16 + l16][quad * 8];
        af[rf][1] = *(const short8*)&T[cur][wr][rf * 16 + l16][32 + quad * 8];
      }
      #pragma unroll
      for (int cf = 0; cf < 4; cf++){
        const short8 b0 = *(const short8*)&T[cur][2 + wc][cf * 16 + l16][quad * 8];
        const short8 b1 = *(const short8*)&T[cur][2 + wc][cf * 16 + l16][32 + quad * 8];
        #pragma unroll
        for (int rf = 0; rf < 4; rf++){
          acc[rf][cf] = MFMA16(af[rf][0], b0, acc[rf][cf]);
          acc[rf][cf] = MFMA16(af[rf][1], b1, acc[rf][cf]);
        }
      }
      __syncthreads();
      cur ^= 1;
    }

    const int h  = (cm0 + wc * 64) >> 6;
    const int nb = n0 + wr * 64;
    bf16 (*Tw)[64] = reinterpret_cast<bf16(*)[64]>(SHRAW + wave * 8192);

    if (mat < 2){
      bf16* Out = (mat == 0) ? Qo : Ko;
      const int stride = (mat == 0) ? NN : KVP;
      #pragma unroll
      for (int rf = 0; rf < 4; rf++)
        #pragma unroll
        for (int cf = 0; cf < 4; cf++)
          #pragma unroll
          for (int r = 0; r < 4; r++)
            Tw[rf * 16 + quad * 4 + r][cf * 16 + l16] =
                __float2bfloat16(acc[rf][cf][r]);
      const int rr = lane >> 2, cs = (lane & 3) * 16;
      #pragma unroll
      for (int k2 = 0; k2 < 4; k2++){
        const int row = rr + k2 * 16;
        bf16* od = Out + (((size_t)b * NHH + h) * stride + nb + row) * HDD + cs;
        *(uint4*)od       = *(const uint4*)&Tw[row][cs];
        *(uint4*)(od + 8) = *(const uint4*)&Tw[row][cs + 8];
      }
    } else {
      #pragma unroll
      for (int cf = 0; cf < 4; cf++)
        #pragma unroll
        for (int rf = 0; rf < 4; rf++)
          #pragma unroll
          for (int r = 0; r < 4; r++)
            Tw[cf * 16 + l16][rf * 16 + quad * 4 + r] =
                __float2bfloat16(acc[rf][cf][r]);
      __syncthreads();
      const int dl = lane >> 2, cseg = (lane & 3) * 16;
      #pragma unroll
      for (int k2 = 0; k2 < 4; k2++){
        const int d = dl + k2 * 16;
        bf16* vd = Vo + (((size_t)b * NHH + h) * HDD + d) * KVP + nb + cseg;
        *(uint4*)vd       = *(const uint4*)&Tw[d][cseg];
        *(uint4*)(vd + 8) = *(const uint4*)&Tw[d][cseg + 8];
      }
    }
  } else {
    // ------------------------------ cross KV (reg-staged, small)
    bf16 (*At)[72] = reinterpret_cast<bf16(*)[72]>(SHRAW);
    bf16 (*Bk)[72] = reinterpret_cast<bf16(*)[72]>(SHRAW + 64 * 72 * 2);
    bf16 (*Bv)[72] = reinterpret_cast<bf16(*)[72]>(SHRAW + 2 * 64 * 72 * 2);
    const int i  = bx - 1536;           // 0..255
    const int h  = i & 7;
    const int l0 = ((i >> 3) & 1) * 64;
    const int b  = i >> 4;

    const bf16* Wkc = Wt + 3 * (size_t)CCH * CCH;
    const bf16* Wvc = Wt + 4 * (size_t)CCH * CCH;

    f32x4 sk[4], sv[4];
    #pragma unroll
    for (int nt = 0; nt < 4; nt++){
      sk[nt] = (f32x4){0.f,0.f,0.f,0.f};
      sv[nt] = (f32x4){0.f,0.f,0.f,0.f};
    }

    const int sr = tid >> 2, sc = (tid & 3) * 16;
    const bf16* p_a  = Tn  + ((size_t)b * LPAD + l0 + sr) * CCH + sc;
    const bf16* p_bk = Wkc + (size_t)(h * 64 + sr) * CCH + sc;
    const bf16* p_bv = Wvc + (size_t)(h * 64 + sr) * CCH + sc;

    uint4 ra0 = *(const uint4*)p_a,   ra1 = *(const uint4*)(p_a + 8);
    uint4 rk0 = *(const uint4*)p_bk,  rk1 = *(const uint4*)(p_bk + 8);
    uint4 rv0 = *(const uint4*)p_bv,  rv1 = *(const uint4*)(p_bv + 8);

    for (int kt = 0; kt < 8; kt++){
      *(uint4*)&At[sr][sc]     = ra0;  *(uint4*)&At[sr][sc + 8] = ra1;
      *(uint4*)&Bk[sr][sc]     = rk0;  *(uint4*)&Bk[sr][sc + 8] = rk1;
      *(uint4*)&Bv[sr][sc]     = rv0;  *(uint4*)&Bv[sr][sc + 8] = rv1;
      if (kt < 7){
        const int k1 = (kt + 1) * 64;
        ra0 = *(const uint4*)(p_a + k1);   ra1 = *(const uint4*)(p_a + k1 + 8);
        rk0 = *(const uint4*)(p_bk + k1);  rk1 = *(const uint4*)(p_bk + k1 + 8);
        rv0 = *(const uint4*)(p_bv + k1);  rv1 = *(const uint4*)(p_bv + k1 + 8);
      }
      __syncthreads();

      const short8 a0 = *(const short8*)&At[wave * 16 + l16][quad * 8];
      const short8 a1 = *(const short8*)&At[wave * 16 + l16][32 + quad * 8];
      #pragma unroll
      for (int nt = 0; nt < 4; nt++){
        const short8 bk0 = *(const short8*)&Bk[nt * 16 + l16][quad * 8];
        const short8 bk1 = *(const short8*)&Bk[nt * 16 + l16][32 + quad * 8];
        sk[nt] = MFMA16(a0, bk0, sk[nt]);
        sk[nt] = MFMA16(a1, bk1, sk[nt]);
        const short8 bv0 = *(const short8*)&Bv[nt * 16 + l16][quad * 8];
        const short8 bv1 = *(const short8*)&Bv[nt * 16 + l16][32 + quad * 8];
        sv[nt] = MFMA16(a0, bv0, sv[nt]);
        sv[nt] = MFMA16(a1, bv1, sv[nt]);
      }
      __syncthreads();
    }

    #pragma unroll
    for (int r = 0; r < 4; r++){
      int kvrow = NN + l0 + wave * 16 + quad * 4 + r;
      bf16* kd = Ko + (((size_t)b * NHH + h) * KVP + kvrow) * HDD + l16;
      #pragma unroll
      for (int nt = 0; nt < 4; nt++)
        kd[nt * 16] = __float2bfloat16(sk[nt][r]);
    }

    __syncthreads();
    #pragma unroll
    for (int nt = 0; nt < 4; nt++)
      #pragma unroll
      for (int r = 0; r < 4; r++)
        Bk[nt * 16 + l16][wave * 16 + quad * 4 + r] = __float2bfloat16(sv[nt][r]);
    __syncthreads();
    {
      int d = tid >> 2, c = (tid & 3) * 16;
      bf16* vd = Vo + (((size_t)b * NHH + h) * HDD + d) * KVP + NN + l0 + c;
      *(uint4*)vd       = *(const uint4*)&Bk[d][c];
      *(uint4*)(vd + 8) = *(const uint4*)&Bk[d][c + 8];
    }
  }
}

// ------- MFMA flash attention, 32x32x16 path (UNCHANGED — control) ----------
__global__ __launch_bounds__(256, 4) void attn_mfma_kernel(
    const bf16* __restrict__ Q, const bf16* __restrict__ K,
    const bf16* __restrict__ Vt, const int* __restrict__ tmask,
    bf16* __restrict__ Ao)
{
  const int tid  = threadIdx.x;
  const int wave = tid >> 6;
  const int lane = tid & 63;
  const int l31  = lane & 31;
  const int hi   = lane >> 5;
  const int bx = blockIdx.x;
  const int q0 = (bx >> 7) * 128;
  const int g  = bx & 127;
  const int h  = g & 7;
  const int b  = g >> 3;

  __shared__ alignas(16) bf16 KV[2][2][64][72];

  const bf16* qp = Q + (((size_t)b * NHH + h) * NN + q0 + wave * 32 + l31) * HDD + hi * 8;
  short8 qf[4];
  qf[0] = *(const short8*)(qp);
  qf[1] = *(const short8*)(qp + 16);
  qf[2] = *(const short8*)(qp + 32);
  qf[3] = *(const short8*)(qp + 48);

  union { unsigned u[4]; short8 s8; } ones;
  ones.u[0] = 0x3F803F80u; ones.u[1] = 0x3F803F80u;
  ones.u[2] = 0x3F803F80u; ones.u[3] = 0x3F803F80u;

  f32x16 zf;
  #pragma unroll
  for (int i = 0; i < 16; i++) zf[i] = 0.f;

  f32x16 o_acc[2], l_acc;
  #pragma unroll
  for (int dt = 0; dt < 2; dt++)
    #pragma unroll
    for (int i = 0; i < 16; i++) o_acc[dt][i] = 0.f;
  #pragma unroll
  for (int i = 0; i < 16; i++) l_acc[i] = 0.f;

  const size_t kbase = ((size_t)b * NHH + h) * KVP;
  const size_t vbase = ((size_t)b * NHH + h) * (size_t)HDD * KVP;

  const int sr = tid >> 2;
  const int sc = (tid & 3) * 16;
  const bf16* kp = K  + (kbase + sr) * HDD + sc;
  const bf16* vp = Vt + vbase + (size_t)sr * KVP + sc;

  uint4 kr0 = *(const uint4*)kp, kr1 = *(const uint4*)(kp + 8);
  uint4 vr0 = *(const uint4*)vp, vr1 = *(const uint4*)(vp + 8);
  *(uint4*)&KV[0][0][sr][sc]     = kr0;
  *(uint4*)&KV[0][0][sr][sc + 8] = kr1;
  *(uint4*)&KV[0][1][sr][sc]     = vr0;
  *(uint4*)&KV[0][1][sr][sc + 8] = vr1;
  kr0 = *(const uint4*)(kp + 4096); kr1 = *(const uint4*)(kp + 4096 + 8);
  vr0 = *(const uint4*)(vp + 64);   vr1 = *(const uint4*)(vp + 64 + 8);
  __syncthreads();

  for (int kt = 0; kt < 18; kt++){
    const int cur = kt & 1;
    if (kt + 1 < 18){
      *(uint4*)&KV[cur ^ 1][0][sr][sc]     = kr0;
      *(uint4*)&KV[cur ^ 1][0][sr][sc + 8] = kr1;
      *(uint4*)&KV[cur ^ 1][1][sr][sc]     = vr0;
      *(uint4*)&KV[cur ^ 1][1][sr][sc + 8] = vr1;
    }
    if (kt + 2 < 18){
      const size_t ko = (size_t)(kt + 2) * 4096;
      const int    vo = (kt + 2) * 64;
      kr0 = *(const uint4*)(kp + ko); kr1 = *(const uint4*)(kp + ko + 8);
      vr0 = *(const uint4*)(vp + vo); vr1 = *(const uint4*)(vp + vo + 8);
    }

    const bf16 (*Ks)[72] = KV[cur][0];
    const bf16 (*Vs)[72] = KV[cur][1];
    const int kv0 = kt * 64;

    #pragma unroll
    for (int t = 0; t < 2; t++){
      const short8 kf0 = *(const short8*)&Ks[t * 32 + l31][hi * 8];
      const short8 kf1 = *(const short8*)&Ks[t * 32 + l31][16 + hi * 8];
      const short8 kf2 = *(const short8*)&Ks[t * 32 + l31][32 + hi * 8];
      const short8 kf3 = *(const short8*)&Ks[t * 32 + l31][48 + hi * 8];
      __builtin_amdgcn_s_setprio(1);
      f32x16 s = MFMA32(kf0, qf[0], zf);
      s = MFMA32(kf1, qf[1], s);
      s = MFMA32(kf2, qf[2], s);
      s = MFMA32(kf3, qf[3], s);
      __builtin_amdgcn_s_setprio(0);

      if (kv0 + 64 > NN){  // boundary tiles: text mask + KV padding
        #pragma unroll
        for (int r = 0; r < 16; r++){
          int idx = kv0 - NN + t * 32 + (r & 3) + 8 * (r >> 2) + 4 * hi;
          int ci = idx < LLT ? idx : LLT - 1;
          float rep = (idx < LLT)
                        ? (tmask[b * LLT + ci] > 0 ? 1e30f : -1e10f)
                        : -1e30f;
          s[r] = fminf(s[r], rep);
        }
      }

      #pragma unroll
      for (int r = 0; r < 16; r++) s[r] = fexp2(s[r]);

      unsigned w0 = pk2(s[0],  s[1]),  w1 = pk2(s[2],  s[3]);
      unsigned w2 = pk2(s[4],  s[5]),  w3 = pk2(s[6],  s[7]);
      unsigned w4 = pk2(s[8],  s[9]),  w5 = pk2(s[10], s[11]);
      unsigned w6 = pk2(s[12], s[13]), w7 = pk2(s[14], s[15]);
      pl32swap(w0, w2);
      pl32swap(w1, w3);
      pl32swap(w4, w6);
      pl32swap(w5, w7);
      union { unsigned u[4]; short8 s8; } pf0, pf1;
      pf0.u[0] = w0; pf0.u[1] = w1; pf0.u[2] = w2; pf0.u[3] = w3;
      pf1.u[0] = w4; pf1.u[1] = w5; pf1.u[2] = w6; pf1.u[3] = w7;

      const short8 vf00 = *(const short8*)&Vs[l31][t * 32 + hi * 8];
      const short8 vf01 = *(const short8*)&Vs[l31][t * 32 + 16 + hi * 8];
      const short8 vf10 = *(const short8*)&Vs[32 + l31][t * 32 + hi * 8];
      const short8 vf11 = *(const short8*)&Vs[32 + l31][t * 32 + 16 + hi * 8];

      __builtin_amdgcn_s_setprio(1);
      l_acc = MFMA32(pf0.s8, ones.s8, l_acc);
      l_acc = MFMA32(pf1.s8, ones.s8, l_acc);
      o_acc[0] = MFMA32(pf0.s8, vf00, o_acc[0]);
      o_acc[0] = MFMA32(pf1.s8, vf01, o_acc[0]);
      o_acc[1] = MFMA32(pf0.s8, vf10, o_acc[1]);
      o_acc[1] = MFMA32(pf1.s8, vf11, o_acc[1]);
      __builtin_amdgcn_s_setprio(0);
    }
    __syncthreads();
  }

  #pragma unroll
  for (int r = 0; r < 16; r++){
    const int ql = (r & 3) + 8 * (r >> 2) + 4 * hi;
    const float linv = 1.f / l_acc[r];
    const int n = q0 + wave * 32 + ql;
    bf16* dst = Ao + ((size_t)b * NN + n) * CCH + h * HDD + l31;
    dst[0]  = __float2bfloat16(o_acc[0][r] * linv);
    dst[32] = __float2bfloat16(o_acc[1][r] * linv);
  }
}

// ------------- output proj + residual, gload_lds-staged 128x128 GEMM --------
// (UNCHANGED from round 9/10)
__global__ __launch_bounds__(256) void outproj_mfma(
    const bf16* __restrict__ A, const bf16* __restrict__ Wt,
    const float* __restrict__ resid, float* __restrict__ out)
{
  __shared__ alignas(16) char SH[36864];
  bf16 (*T)[64][64] = reinterpret_cast<bf16(*)[64][64]>(SH);
  const int tid  = threadIdx.x;
  const int wave = tid >> 6, lane = tid & 63;
  const int l16 = lane & 15, quad = lane >> 4;
  const int wr = wave >> 1, wc = wave & 1;
  const int bx = blockIdx.x;
  const int c0 = (bx >> 7) * 128;     // 0..511
  const int g0 = (bx & 127) * 128;    // 0..16383

  const bf16* Bw = Wt + (size_t)5 * CCH * CCH + (size_t)c0 * CCH;

  f32x4 acc[4][4];
  #pragma unroll
  for (int rf = 0; rf < 4; rf++)
    #pragma unroll
    for (int cf = 0; cf < 4; cf++) acc[rf][cf] = (f32x4){0.f,0.f,0.f,0.f};

  const int lrow = lane >> 3, lcol = (lane & 7) * 8;
  const bf16* srcbase = (wave < 2)
      ? A  + ((size_t)g0 + wave * 64) * CCH
      : Bw + (size_t)((wave - 2) * 64) * CCH;

  for (int kt = 0; kt < 8; kt++){
    const int kc = kt * 64;
    #pragma unroll
    for (int c = 0; c < 8; c++){
      const bf16* g = srcbase + (size_t)(c * 8 + lrow) * CCH + kc + lcol;
      gload16(g, &T[wave][c * 8][0]);
    }
    __syncthreads();

    short8 af[4][2];
    #pragma unroll
    for (int rf = 0; rf < 4; rf++){
      af[rf][0] = *(const short8*)&T[wr][rf * 16 + l16][quad * 8];
      af[rf][1] = *(const short8*)&T[wr][rf * 16 + l16][32 + quad * 8];
    }
    #pragma unroll
    for (int cf = 0; cf < 4; cf++){
      const short8 b0 = *(const short8*)&T[2 + wc][cf * 16 + l16][quad * 8];
      const short8 b1 = *(const short8*)&T[2 + wc][cf * 16 + l16][32 + quad * 8];
      #pragma unroll
      for (int rf = 0; rf < 4; rf++){
        acc[rf][cf] = MFMA16(af[rf][0], b0, acc[rf][cf]);
        acc[rf][cf] = MFMA16(af[rf][1], b1, acc[rf][cf]);
      }
    }
    __syncthreads();
  }

  // -------- vectorized epilogue (per-wave region SH + wave*8704, f32[32][68])
  float (*Tf)[68] = reinterpret_cast<float(*)[68]>(SH + wave * 8704);
  const int cg = (lane & 15) * 4;     // float4-granular col within 64
  #pragma unroll
  for (int hf = 0; hf < 2; hf++){
    #pragma unroll
    for (int rf = 0; rf < 2; rf++)
      #pragma unroll
      for (int cf = 0; cf < 4; cf++)
        #pragma unroll
        for (int r = 0; r < 4; r++)
          Tf[rf * 16 + quad * 4 + r][cf * 16 + l16] = acc[hf * 2 + rf][cf][r];
    // intra-wave RAW through same pointer: compiler orders via lgkmcnt
    #pragma unroll
    for (int k = 0; k < 8; k++){
      const int row32 = k * 4 + quad;
      const size_t grow = (size_t)g0 + wr * 64 + hf * 32 + row32;
      const int gcol = c0 + wc * 64 + cg;
      float4 v  = *(const float4*)&Tf[row32][cg];
      float4 rz = *(const float4*)&resid[grow * CCH + gcol];
      v.x += rz.x; v.y += rz.y; v.z += rz.z; v.w += rz.w;
      *(float4*)&out[grow * CCH + gcol] = v;
    }
    if (hf == 0){
      // WAR: all hf=0 reads drained before hf=1 overwrites the same rows
      asm volatile("s_waitcnt lgkmcnt(0)" ::: "memory");
      __builtin_amdgcn_sched_barrier(0);
    }
  }
}

// --------------------------------------------------------------- launcher
extern "C" void kernel_launch(void* const* d_in, const int* in_sizes, int n_in,
                              void* d_out, int out_size, void* d_ws, size_t ws_size,
                              hipStream_t stream)
{
  const float* x     = (const float*)d_in[0];
  const float* txt   = (const float*)d_in[1];
  const int*   tmask = (const int*)d_in[2];
  const float* gqs   = (const float*)d_in[3];
  const float* gqb   = (const float*)d_in[4];
  const float* gks   = (const float*)d_in[5];
  const float* gkb   = (const float*)d_in[6];
  const float* gts   = (const float*)d_in[7];
  const float* gtb   = (const float*)d_in[8];
  const float* Wq    = (const float*)d_in[9];
  const float* Wks   = (const float*)d_in[10];
  const float* Wvs   = (const float*)d_in[11];
  const float* Wkc   = (const float*)d_in[12];
  const float* Wvc   = (const float*)d_in[13];
  const float* Wout  = (const float*)d_in[14];

  float* stats = (float*)d_ws;                            // 2048 floats (unused, kept for layout)
  bf16* WtAll = (bf16*)(stats + 2048);                    // 6 * 512 * 512
  bf16* Xq  = WtAll + (size_t)6 * CCH * CCH;
  bf16* Xkv = Xq  + (size_t)BB * NN * CCH;
  bf16* Tn  = Xkv + (size_t)BB * NN * CCH;
  bf16* Qw  = Tn  + (size_t)BB * LPAD * CCH;
  bf16* Kw  = Qw  + (size_t)BB * NHH * NN * HDD;
  bf16* Vw  = Kw  + (size_t)BB * NHH * KVP * HDD;         // [b,h,hd,kvp]
  bf16* Aw  = Xq;                                         // alias: Xq dead after proj

  gn_norm_kernel<<<1408, 256, 0, stream>>>(
      x, txt, gqs, gqb, gks, gkb, gts, gtb,
      Wq, Wks, Wvs, Wkc, Wvc, Wout, WtAll, Xq, Xkv, Tn);
  proj_all_mfma<<<1792, 256, 0, stream>>>(
      Xq, Xkv, Tn, WtAll, Qw, Kw, Vw);
  attn_mfma_kernel<<<1024, 256, 0, stream>>>(Qw, Kw, Vw, tmask, Aw);
  outproj_mfma<<<512, 256, 0, stream>>>(Aw, WtAll, x, (float*)d_out);
}

// Round 12
// 254.745 us; speedup vs baseline: 1.0193x; 1.0193x over previous
//
#include <hip/hip_runtime.h>
#include <hip/hip_bf16.h>

typedef __hip_bfloat16 bf16;
typedef __attribute__((ext_vector_type(8))) short short8;
typedef __attribute__((ext_vector_type(4))) float f32x4;
typedef __attribute__((ext_vector_type(16))) float f32x16;
#define MFMA16(a, b, c) __builtin_amdgcn_mfma_f32_16x16x32_bf16(a, b, c, 0, 0, 0)
#define MFMA32(a, b, c) __builtin_amdgcn_mfma_f32_32x32x16_bf16(a, b, c, 0, 0, 0)

#define BB   16
#define CCH  512
#define NN   1024
#define LLT  77
#define LPAD 128
#define NHH  8
#define HDD  64
#define GGN  32
#define NKV  1101   /* 1024 + 77 */
#define KVP  1152   /* 18 * 64, padded KV rows */
#define QSC  0.18033688f  /* 0.125 * log2(e) */

__device__ __forceinline__ unsigned short f2bu(float f){
  bf16 h = __float2bfloat16(f);
  return *reinterpret_cast<unsigned short*>(&h);
}

// single-instruction packed f32->bf16 (RNE)
__device__ __forceinline__ unsigned pk2(float lo, float hi){
  unsigned r;
  asm("v_cvt_pk_bf16_f32 %0, %1, %2" : "=v"(r) : "v"(lo), "v"(hi));
  return r;
}

// raw v_exp_f32 (exp2)
__device__ __forceinline__ float fexp2(float x){
  float r;
  asm("v_exp_f32 %0, %1" : "=v"(r) : "v"(x));
  return r;
}

// v_permlane32_swap_b32: new_a = {a.lo, b.lo}, new_b = {a.hi, b.hi}
__device__ __forceinline__ void pl32swap(unsigned &a, unsigned &b){
  asm("v_permlane32_swap_b32 %0, %1" : "+v"(a), "+v"(b));
}

// async global->LDS DMA, 16B per lane: lds dest = uniform base + lane*16,
// global src is per-lane.
__device__ __forceinline__ void gload16(const bf16* g, bf16* l){
  __builtin_amdgcn_global_load_lds(
      (const __attribute__((address_space(1))) unsigned int*)g,
      (__attribute__((address_space(3))) unsigned int*)l,
      16, 0, 0);
}

// ---- pre: img GN stats -> per-(b,ch) affine coeffs (blocks 0-511),
//          text GN fused norm -> Tn (512-1023, two-pass, slice is tiny),
//          weight prep -> Wt (1024-1407).
// Coeffs fold GroupNorm+scale+bias(+QSC) into one fma/elem for the
// projection kernel:  out = x * cA[b][ch] + cB[b][ch].
__global__ __launch_bounds__(256) void pre_kernel(
    const float* __restrict__ x, const float* __restrict__ t,
    const float* __restrict__ gqs, const float* __restrict__ gqb,
    const float* __restrict__ gks, const float* __restrict__ gkb,
    const float* __restrict__ gts, const float* __restrict__ gtb,
    const float* __restrict__ W0, const float* __restrict__ W1,
    const float* __restrict__ W2, const float* __restrict__ W3,
    const float* __restrict__ W4, const float* __restrict__ W5,
    bf16* __restrict__ Wt,
    float* __restrict__ cAq, float* __restrict__ cBq,
    float* __restrict__ cAk, float* __restrict__ cBk,
    bf16* __restrict__ Tn)
{
  __shared__ float sh1[256], sh2[256], mr[2];
  __shared__ alignas(16) float Ws[64][68];
  const int tid = threadIdx.x;
  const int bid = blockIdx.x;

  if (bid < 512){
    // ------------------------------ img GN stats + coeffs
    const int b = bid >> 5, g = bid & 31;
    const float* xb = x + (size_t)b * NN * CCH + g * 16;
    float s = 0.f, s2 = 0.f;
    for (int i = tid; i < 4096; i += 256){
      const int n = i >> 2, cq = (i & 3) * 4;
      float4 v = *(const float4*)(xb + (size_t)n * CCH + cq);
      s  += v.x + v.y + v.z + v.w;
      s2 += v.x * v.x + v.y * v.y + v.z * v.z + v.w * v.w;
    }
    sh1[tid] = s; sh2[tid] = s2;
    __syncthreads();
    for (int off = 128; off > 0; off >>= 1){
      if (tid < off){ sh1[tid] += sh1[tid + off]; sh2[tid] += sh2[tid + off]; }
      __syncthreads();
    }
    if (tid == 0){
      const float inv = 1.f / 16384.f;
      const float m = sh1[0] * inv;
      mr[0] = m;
      mr[1] = rsqrtf(sh2[0] * inv - m * m + 1e-6f);
    }
    __syncthreads();
    if (tid < 16){
      const int ch = g * 16 + tid;
      const float m = mr[0], r = mr[1];
      const float aq = r * gqs[ch] * QSC;
      cAq[b * CCH + ch] = aq;
      cBq[b * CCH + ch] = gqb[ch] * QSC - m * aq;
      const float ak = r * gks[ch];
      cAk[b * CCH + ch] = ak;
      cBk[b * CCH + ch] = gkb[ch] - m * ak;
    }
  } else if (bid < 1024){
    // ------------------------------ text GN fused (stats + Tn, pad to 128)
    const int b = (bid - 512) >> 5, g = (bid - 512) & 31;
    const float* tb = t + (size_t)b * LLT * CCH + g * 16;
    float s = 0.f, s2 = 0.f;
    for (int i = tid; i < 308; i += 256){  // 77 rows x 4 chunks
      const int l = i >> 2, cq = (i & 3) * 4;
      float4 v = *(const float4*)(tb + (size_t)l * CCH + cq);
      s  += v.x + v.y + v.z + v.w;
      s2 += v.x * v.x + v.y * v.y + v.z * v.z + v.w * v.w;
    }
    sh1[tid] = s; sh2[tid] = s2;
    __syncthreads();
    for (int off = 128; off > 0; off >>= 1){
      if (tid < off){ sh1[tid] += sh1[tid + off]; sh2[tid] += sh2[tid + off]; }
      __syncthreads();
    }
    if (tid == 0){
      const float inv = 1.f / (float)(LLT * 16);
      const float m = sh1[0] * inv;
      mr[0] = m;
      mr[1] = rsqrtf(sh2[0] * inv - m * m + 1e-6f);
    }
    __syncthreads();
    const float m = mr[0], r = mr[1];
    const int ch0 = g * 16;
    for (int i = tid; i < 512; i += 256){  // 128 rows x 4 chunks
      const int l = i >> 2, cq = (i & 3) * 4;
      const int ch = ch0 + cq;
      uint2 o;
      if (l < LLT){
        float4 v  = *(const float4*)(tb + (size_t)l * CCH + cq);
        float4 sv = *(const float4*)(gts + ch), bv = *(const float4*)(gtb + ch);
        o.x = pk2((v.x - m) * r * sv.x + bv.x, (v.y - m) * r * sv.y + bv.y);
        o.y = pk2((v.z - m) * r * sv.z + bv.z, (v.w - m) * r * sv.w + bv.w);
      } else {
        o.x = 0u; o.y = 0u;
      }
      *(uint2*)(Tn + ((size_t)b * LPAD + l) * CCH + ch) = o;
    }
  } else {
    // ------------------------------ weight prep (unchanged math)
    const int i = bid - 1024;            // 0..383
    const int wsel = i >> 6;             // 0..5
    const int rem  = i & 63;
    const int n0 = (rem & 7) * 64, k0 = (rem >> 3) * 64;
    const float* W = wsel == 0 ? W0 : wsel == 1 ? W1 : wsel == 2 ? W2 :
                     wsel == 3 ? W3 : wsel == 4 ? W4 : W5;
    bf16* dst = Wt + (size_t)wsel * CCH * CCH;

    const int rr = tid >> 2, c = (tid & 3) * 16;
    const float* src = W + (size_t)(k0 + rr) * CCH + n0 + c;
    *(float4*)&Ws[rr][c]      = *(const float4*)(src);
    *(float4*)&Ws[rr][c + 4]  = *(const float4*)(src + 4);
    *(float4*)&Ws[rr][c + 8]  = *(const float4*)(src + 8);
    *(float4*)&Ws[rr][c + 12] = *(const float4*)(src + 12);
    __syncthreads();

    const int nr = tid >> 2, kc = (tid & 3) * 16;
    uint4 o0, o1;
    o0.x = pk2(Ws[kc + 0][nr],  Ws[kc + 1][nr]);
    o0.y = pk2(Ws[kc + 2][nr],  Ws[kc + 3][nr]);
    o0.z = pk2(Ws[kc + 4][nr],  Ws[kc + 5][nr]);
    o0.w = pk2(Ws[kc + 6][nr],  Ws[kc + 7][nr]);
    o1.x = pk2(Ws[kc + 8][nr],  Ws[kc + 9][nr]);
    o1.y = pk2(Ws[kc + 10][nr], Ws[kc + 11][nr]);
    o1.z = pk2(Ws[kc + 12][nr], Ws[kc + 13][nr]);
    o1.w = pk2(Ws[kc + 14][nr], Ws[kc + 15][nr]);
    bf16* d = dst + (size_t)(n0 + nr) * CCH + k0 + kc;
    *(uint4*)d = o0;
    *(uint4*)(d + 8) = o1;
  }
}

// -------- fused norm+projections: self QKV (0-1535) + cross KV (1536-1791) --
// Self: 128x128-tile GEMM, double-buffered. A-operand is normalized IN-FLIGHT
// from raw f32 x (L3-hot after pre): T14 split — f32 loads issued before the
// MFMA block, one-fma normalize (coeffs) + pk2 + ds_write after. A tiles use
// a T2 XOR swizzle (chunk ^= row&7, write AND read) since [64][64] can't be
// padded next to the linear gload_lds B tiles. B staged by waves 2,3 via
// gload_lds. ONE barrier per K-step. Replaces the norm_all kernel entirely.
__global__ __launch_bounds__(256) void proj_all_mfma(
    const float* __restrict__ x,
    const float* __restrict__ cAq, const float* __restrict__ cBq,
    const float* __restrict__ cAk, const float* __restrict__ cBk,
    const bf16* __restrict__ Tn, const bf16* __restrict__ Wt,
    bf16* __restrict__ Qo, bf16* __restrict__ Ko, bf16* __restrict__ Vo)
{
  __shared__ alignas(16) char SHRAW[65536];
  const int tid  = threadIdx.x;
  const int wave = tid >> 6, lane = tid & 63;
  const int l16 = lane & 15, quad = lane >> 4;
  const int bx = blockIdx.x;

  if (bx < 1536){
    bf16 (*T)[4][64][64] = reinterpret_cast<bf16(*)[4][64][64]>(SHRAW);
    const int wr = wave >> 1, wc = wave & 1;
    const int ct = bx >> 7;             // 0..11
    const int rt = bx & 127;            // 0..127
    const int mat = ct >> 2;            // 0=Q, 1=K, 2=V
    const int cm0 = (ct & 3) * 128;
    const int b  = rt >> 3;
    const int n0 = (rt & 7) * 128;

    const bf16*  Bw   = Wt + (size_t)mat * CCH * CCH + (size_t)cm0 * CCH;
    const float* xsrc = x + ((size_t)b * NN + n0) * CCH;
    const float* cA   = (mat == 0) ? cAq : cAk;
    const float* cB   = (mat == 0) ? cBq : cBk;

    f32x4 acc[4][4];
    #pragma unroll
    for (int rf = 0; rf < 4; rf++)
      #pragma unroll
      for (int cf = 0; cf < 4; cf++) acc[rf][cf] = (f32x4){0.f,0.f,0.f,0.f};

    const int sr = tid >> 2, sc4 = (tid & 3) * 16;
    const int c0ch = sc4 >> 3;          // first 16B-chunk index (0,2,4,6)
    const int lrow = lane >> 3, lcol = (lane & 7) * 8;
    const bf16* bsrc = Bw + (size_t)(((wave - 2) & 3) * 64) * CCH;

    float4 av[2][4];
    auto earlyA = [&](int kc){
      const float* s0 = xsrc + (size_t)sr * CCH + kc + sc4;
      const float* s1 = s0 + (size_t)64 * CCH;
      av[0][0] = *(const float4*)s0;       av[0][1] = *(const float4*)(s0 + 4);
      av[0][2] = *(const float4*)(s0 + 8); av[0][3] = *(const float4*)(s0 + 12);
      av[1][0] = *(const float4*)s1;       av[1][1] = *(const float4*)(s1 + 4);
      av[1][2] = *(const float4*)(s1 + 8); av[1][3] = *(const float4*)(s1 + 12);
    };
    auto lateA = [&](int kc, int buf){
      const int ch = kc + sc4;
      const float* pa = cA + b * CCH + ch;
      const float* pb = cB + b * CCH + ch;
      const float4 a0 = *(const float4*)pa,       a1 = *(const float4*)(pa + 4);
      const float4 a2 = *(const float4*)(pa + 8), a3 = *(const float4*)(pa + 12);
      const float4 b0 = *(const float4*)pb,       b1 = *(const float4*)(pb + 4);
      const float4 b2 = *(const float4*)(pb + 8), b3 = *(const float4*)(pb + 12);
      #pragma unroll
      for (int a = 0; a < 2; a++){
        uint4 w0, w1;
        w0.x = pk2(av[a][0].x * a0.x + b0.x, av[a][0].y * a0.y + b0.y);
        w0.y = pk2(av[a][0].z * a0.z + b0.z, av[a][0].w * a0.w + b0.w);
        w0.z = pk2(av[a][1].x * a1.x + b1.x, av[a][1].y * a1.y + b1.y);
        w0.w = pk2(av[a][1].z * a1.z + b1.z, av[a][1].w * a1.w + b1.w);
        w1.x = pk2(av[a][2].x * a2.x + b2.x, av[a][2].y * a2.y + b2.y);
        w1.y = pk2(av[a][2].z * a2.z + b2.z, av[a][2].w * a2.w + b2.w);
        w1.z = pk2(av[a][3].x * a3.x + b3.x, av[a][3].y * a3.y + b3.y);
        w1.w = pk2(av[a][3].z * a3.z + b3.z, av[a][3].w * a3.w + b3.w);
        bf16* base = &T[buf][a][sr][0];
        *(uint4*)(base + ((( c0ch     ) ^ (sr & 7)) << 3)) = w0;
        *(uint4*)(base + (((c0ch + 1) ^ (sr & 7)) << 3)) = w1;
      }
    };
    auto stageB = [&](int kc, int buf){
      if (wave >= 2){
        #pragma unroll
        for (int c = 0; c < 8; c++)
          gload16(bsrc + (size_t)(c * 8 + lrow) * CCH + kc + lcol,
                  &T[buf][wave][c * 8][0]);
      }
    };

    // prologue: tile 0 into buf 0
    stageB(0, 0);
    earlyA(0);
    lateA(0, 0);
    __syncthreads();

    int cur = 0;
    for (int kt = 0; kt < 8; kt++){
      if (kt < 7){
        stageB((kt + 1) * 64, cur ^ 1);   // async B issues
        earlyA((kt + 1) * 64);            // A f32 loads in flight over MFMA
      }

      short8 af[4][2];
      #pragma unroll
      for (int rf = 0; rf < 4; rf++){
        const int rr = rf * 16 + l16;
        af[rf][0] = *(const short8*)&T[cur][wr][rr][((quad    ) ^ (rr & 7)) << 3];
        af[rf][1] = *(const short8*)&T[cur][wr][rr][((quad + 4) ^ (rr & 7)) << 3];
      }
      #pragma unroll
      for (int cf = 0; cf < 4; cf++){
        const short8 b0 = *(const short8*)&T[cur][2 + wc][cf * 16 + l16][quad * 8];
        const short8 b1 = *(const short8*)&T[cur][2 + wc][cf * 16 + l16][32 + quad * 8];
        #pragma unroll
        for (int rf = 0; rf < 4; rf++){
          acc[rf][cf] = MFMA16(af[rf][0], b0, acc[rf][cf]);
          acc[rf][cf] = MFMA16(af[rf][1], b1, acc[rf][cf]);
        }
      }

      if (kt < 7) lateA((kt + 1) * 64, cur ^ 1);  // normalize + ds_write late
      __syncthreads();   // drains vmcnt (B) + lgkm (A writes); WAR safe
      cur ^= 1;
    }

    const int h  = (cm0 + wc * 64) >> 6;
    const int nb = n0 + wr * 64;
    bf16 (*Tw)[64] = reinterpret_cast<bf16(*)[64]>(SHRAW + wave * 8192);

    if (mat < 2){
      bf16* Out = (mat == 0) ? Qo : Ko;
      const int stride = (mat == 0) ? NN : KVP;
      #pragma unroll
      for (int rf = 0; rf < 4; rf++)
        #pragma unroll
        for (int cf = 0; cf < 4; cf++)
          #pragma unroll
          for (int r = 0; r < 4; r++)
            Tw[rf * 16 + quad * 4 + r][cf * 16 + l16] =
                __float2bfloat16(acc[rf][cf][r]);
      const int rr = lane >> 2, cs = (lane & 3) * 16;
      #pragma unroll
      for (int k2 = 0; k2 < 4; k2++){
        const int row = rr + k2 * 16;
        bf16* od = Out + (((size_t)b * NHH + h) * stride + nb + row) * HDD + cs;
        *(uint4*)od       = *(const uint4*)&Tw[row][cs];
        *(uint4*)(od + 8) = *(const uint4*)&Tw[row][cs + 8];
      }
    } else {
      #pragma unroll
      for (int cf = 0; cf < 4; cf++)
        #pragma unroll
        for (int rf = 0; rf < 4; rf++)
          #pragma unroll
          for (int r = 0; r < 4; r++)
            Tw[cf * 16 + l16][rf * 16 + quad * 4 + r] =
                __float2bfloat16(acc[rf][cf][r]);
      __syncthreads();
      const int dl = lane >> 2, cseg = (lane & 3) * 16;
      #pragma unroll
      for (int k2 = 0; k2 < 4; k2++){
        const int d = dl + k2 * 16;
        bf16* vd = Vo + (((size_t)b * NHH + h) * HDD + d) * KVP + nb + cseg;
        *(uint4*)vd       = *(const uint4*)&Tw[d][cseg];
        *(uint4*)(vd + 8) = *(const uint4*)&Tw[d][cseg + 8];
      }
    }
  } else {
    // ------------------------------ cross KV (reg-staged, small; reads Tn)
    bf16 (*At)[72] = reinterpret_cast<bf16(*)[72]>(SHRAW);
    bf16 (*Bk)[72] = reinterpret_cast<bf16(*)[72]>(SHRAW + 64 * 72 * 2);
    bf16 (*Bv)[72] = reinterpret_cast<bf16(*)[72]>(SHRAW + 2 * 64 * 72 * 2);
    const int i  = bx - 1536;           // 0..255
    const int h  = i & 7;
    const int l0 = ((i >> 3) & 1) * 64;
    const int b  = i >> 4;

    const bf16* Wkc = Wt + 3 * (size_t)CCH * CCH;
    const bf16* Wvc = Wt + 4 * (size_t)CCH * CCH;

    f32x4 sk[4], sv[4];
    #pragma unroll
    for (int nt = 0; nt < 4; nt++){
      sk[nt] = (f32x4){0.f,0.f,0.f,0.f};
      sv[nt] = (f32x4){0.f,0.f,0.f,0.f};
    }

    const int sr = tid >> 2, sc = (tid & 3) * 16;
    const bf16* p_a  = Tn  + ((size_t)b * LPAD + l0 + sr) * CCH + sc;
    const bf16* p_bk = Wkc + (size_t)(h * 64 + sr) * CCH + sc;
    const bf16* p_bv = Wvc + (size_t)(h * 64 + sr) * CCH + sc;

    uint4 ra0 = *(const uint4*)p_a,   ra1 = *(const uint4*)(p_a + 8);
    uint4 rk0 = *(const uint4*)p_bk,  rk1 = *(const uint4*)(p_bk + 8);
    uint4 rv0 = *(const uint4*)p_bv,  rv1 = *(const uint4*)(p_bv + 8);

    for (int kt = 0; kt < 8; kt++){
      *(uint4*)&At[sr][sc]     = ra0;  *(uint4*)&At[sr][sc + 8] = ra1;
      *(uint4*)&Bk[sr][sc]     = rk0;  *(uint4*)&Bk[sr][sc + 8] = rk1;
      *(uint4*)&Bv[sr][sc]     = rv0;  *(uint4*)&Bv[sr][sc + 8] = rv1;
      if (kt < 7){
        const int k1 = (kt + 1) * 64;
        ra0 = *(const uint4*)(p_a + k1);   ra1 = *(const uint4*)(p_a + k1 + 8);
        rk0 = *(const uint4*)(p_bk + k1);  rk1 = *(const uint4*)(p_bk + k1 + 8);
        rv0 = *(const uint4*)(p_bv + k1);  rv1 = *(const uint4*)(p_bv + k1 + 8);
      }
      __syncthreads();

      const short8 a0 = *(const short8*)&At[wave * 16 + l16][quad * 8];
      const short8 a1 = *(const short8*)&At[wave * 16 + l16][32 + quad * 8];
      #pragma unroll
      for (int nt = 0; nt < 4; nt++){
        const short8 bk0 = *(const short8*)&Bk[nt * 16 + l16][quad * 8];
        const short8 bk1 = *(const short8*)&Bk[nt * 16 + l16][32 + quad * 8];
        sk[nt] = MFMA16(a0, bk0, sk[nt]);
        sk[nt] = MFMA16(a1, bk1, sk[nt]);
        const short8 bv0 = *(const short8*)&Bv[nt * 16 + l16][quad * 8];
        const short8 bv1 = *(const short8*)&Bv[nt * 16 + l16][32 + quad * 8];
        sv[nt] = MFMA16(a0, bv0, sv[nt]);
        sv[nt] = MFMA16(a1, bv1, sv[nt]);
      }
      __syncthreads();
    }

    #pragma unroll
    for (int r = 0; r < 4; r++){
      int kvrow = NN + l0 + wave * 16 + quad * 4 + r;
      bf16* kd = Ko + (((size_t)b * NHH + h) * KVP + kvrow) * HDD + l16;
      #pragma unroll
      for (int nt = 0; nt < 4; nt++)
        kd[nt * 16] = __float2bfloat16(sk[nt][r]);
    }

    __syncthreads();
    #pragma unroll
    for (int nt = 0; nt < 4; nt++)
      #pragma unroll
      for (int r = 0; r < 4; r++)
        Bk[nt * 16 + l16][wave * 16 + quad * 4 + r] = __float2bfloat16(sv[nt][r]);
    __syncthreads();
    {
      int d = tid >> 2, c = (tid & 3) * 16;
      bf16* vd = Vo + (((size_t)b * NHH + h) * HDD + d) * KVP + NN + l0 + c;
      *(uint4*)vd       = *(const uint4*)&Bk[d][c];
      *(uint4*)(vd + 8) = *(const uint4*)&Bk[d][c + 8];
    }
  }
}

// ------- MFMA flash attention, 32x32x16 path (UNCHANGED — control) ----------
__global__ __launch_bounds__(256, 4) void attn_mfma_kernel(
    const bf16* __restrict__ Q, const bf16* __restrict__ K,
    const bf16* __restrict__ Vt, const int* __restrict__ tmask,
    bf16* __restrict__ Ao)
{
  const int tid  = threadIdx.x;
  const int wave = tid >> 6;
  const int lane = tid & 63;
  const int l31  = lane & 31;
  const int hi   = lane >> 5;
  const int bx = blockIdx.x;
  const int q0 = (bx >> 7) * 128;
  const int g  = bx & 127;
  const int h  = g & 7;
  const int b  = g >> 3;

  __shared__ alignas(16) bf16 KV[2][2][64][72];

  const bf16* qp = Q + (((size_t)b * NHH + h) * NN + q0 + wave * 32 + l31) * HDD + hi * 8;
  short8 qf[4];
  qf[0] = *(const short8*)(qp);
  qf[1] = *(const short8*)(qp + 16);
  qf[2] = *(const short8*)(qp + 32);
  qf[3] = *(const short8*)(qp + 48);

  union { unsigned u[4]; short8 s8; } ones;
  ones.u[0] = 0x3F803F80u; ones.u[1] = 0x3F803F80u;
  ones.u[2] = 0x3F803F80u; ones.u[3] = 0x3F803F80u;

  f32x16 zf;
  #pragma unroll
  for (int i = 0; i < 16; i++) zf[i] = 0.f;

  f32x16 o_acc[2], l_acc;
  #pragma unroll
  for (int dt = 0; dt < 2; dt++)
    #pragma unroll
    for (int i = 0; i < 16; i++) o_acc[dt][i] = 0.f;
  #pragma unroll
  for (int i = 0; i < 16; i++) l_acc[i] = 0.f;

  const size_t kbase = ((size_t)b * NHH + h) * KVP;
  const size_t vbase = ((size_t)b * NHH + h) * (size_t)HDD * KVP;

  const int sr = tid >> 2;
  const int sc = (tid & 3) * 16;
  const bf16* kp = K  + (kbase + sr) * HDD + sc;
  const bf16* vp = Vt + vbase + (size_t)sr * KVP + sc;

  uint4 kr0 = *(const uint4*)kp, kr1 = *(const uint4*)(kp + 8);
  uint4 vr0 = *(const uint4*)vp, vr1 = *(const uint4*)(vp + 8);
  *(uint4*)&KV[0][0][sr][sc]     = kr0;
  *(uint4*)&KV[0][0][sr][sc + 8] = kr1;
  *(uint4*)&KV[0][1][sr][sc]     = vr0;
  *(uint4*)&KV[0][1][sr][sc + 8] = vr1;
  kr0 = *(const uint4*)(kp + 4096); kr1 = *(const uint4*)(kp + 4096 + 8);
  vr0 = *(const uint4*)(vp + 64);   vr1 = *(const uint4*)(vp + 64 + 8);
  __syncthreads();

  for (int kt = 0; kt < 18; kt++){
    const int cur = kt & 1;
    if (kt + 1 < 18){
      *(uint4*)&KV[cur ^ 1][0][sr][sc]     = kr0;
      *(uint4*)&KV[cur ^ 1][0][sr][sc + 8] = kr1;
      *(uint4*)&KV[cur ^ 1][1][sr][sc]     = vr0;
      *(uint4*)&KV[cur ^ 1][1][sr][sc + 8] = vr1;
    }
    if (kt + 2 < 18){
      const size_t ko = (size_t)(kt + 2) * 4096;
      const int    vo = (kt + 2) * 64;
      kr0 = *(const uint4*)(kp + ko); kr1 = *(const uint4*)(kp + ko + 8);
      vr0 = *(const uint4*)(vp + vo); vr1 = *(const uint4*)(vp + vo + 8);
    }

    const bf16 (*Ks)[72] = KV[cur][0];
    const bf16 (*Vs)[72] = KV[cur][1];
    const int kv0 = kt * 64;

    #pragma unroll
    for (int t = 0; t < 2; t++){
      const short8 kf0 = *(const short8*)&Ks[t * 32 + l31][hi * 8];
      const short8 kf1 = *(const short8*)&Ks[t * 32 + l31][16 + hi * 8];
      const short8 kf2 = *(const short8*)&Ks[t * 32 + l31][32 + hi * 8];
      const short8 kf3 = *(const short8*)&Ks[t * 32 + l31][48 + hi * 8];
      __builtin_amdgcn_s_setprio(1);
      f32x16 s = MFMA32(kf0, qf[0], zf);
      s = MFMA32(kf1, qf[1], s);
      s = MFMA32(kf2, qf[2], s);
      s = MFMA32(kf3, qf[3], s);
      __builtin_amdgcn_s_setprio(0);

      if (kv0 + 64 > NN){  // boundary tiles: text mask + KV padding
        #pragma unroll
        for (int r = 0; r < 16; r++){
          int idx = kv0 - NN + t * 32 + (r & 3) + 8 * (r >> 2) + 4 * hi;
          int ci = idx < LLT ? idx : LLT - 1;
          float rep = (idx < LLT)
                        ? (tmask[b * LLT + ci] > 0 ? 1e30f : -1e10f)
                        : -1e30f;
          s[r] = fminf(s[r], rep);
        }
      }

      #pragma unroll
      for (int r = 0; r < 16; r++) s[r] = fexp2(s[r]);

      unsigned w0 = pk2(s[0],  s[1]),  w1 = pk2(s[2],  s[3]);
      unsigned w2 = pk2(s[4],  s[5]),  w3 = pk2(s[6],  s[7]);
      unsigned w4 = pk2(s[8],  s[9]),  w5 = pk2(s[10], s[11]);
      unsigned w6 = pk2(s[12], s[13]), w7 = pk2(s[14], s[15]);
      pl32swap(w0, w2);
      pl32swap(w1, w3);
      pl32swap(w4, w6);
      pl32swap(w5, w7);
      union { unsigned u[4]; short8 s8; } pf0, pf1;
      pf0.u[0] = w0; pf0.u[1] = w1; pf0.u[2] = w2; pf0.u[3] = w3;
      pf1.u[0] = w4; pf1.u[1] = w5; pf1.u[2] = w6; pf1.u[3] = w7;

      const short8 vf00 = *(const short8*)&Vs[l31][t * 32 + hi * 8];
      const short8 vf01 = *(const short8*)&Vs[l31][t * 32 + 16 + hi * 8];
      const short8 vf10 = *(const short8*)&Vs[32 + l31][t * 32 + hi * 8];
      const short8 vf11 = *(const short8*)&Vs[32 + l31][t * 32 + 16 + hi * 8];

      __builtin_amdgcn_s_setprio(1);
      l_acc = MFMA32(pf0.s8, ones.s8, l_acc);
      l_acc = MFMA32(pf1.s8, ones.s8, l_acc);
      o_acc[0] = MFMA32(pf0.s8, vf00, o_acc[0]);
      o_acc[0] = MFMA32(pf1.s8, vf01, o_acc[0]);
      o_acc[1] = MFMA32(pf0.s8, vf10, o_acc[1]);
      o_acc[1] = MFMA32(pf1.s8, vf11, o_acc[1]);
      __builtin_amdgcn_s_setprio(0);
    }
    __syncthreads();
  }

  #pragma unroll
  for (int r = 0; r < 16; r++){
    const int ql = (r & 3) + 8 * (r >> 2) + 4 * hi;
    const float linv = 1.f / l_acc[r];
    const int n = q0 + wave * 32 + ql;
    bf16* dst = Ao + ((size_t)b * NN + n) * CCH + h * HDD + l31;
    dst[0]  = __float2bfloat16(o_acc[0][r] * linv);
    dst[32] = __float2bfloat16(o_acc[1][r] * linv);
  }
}

// ------------- output proj + residual, gload_lds-staged 128x128 GEMM --------
// (UNCHANGED from rounds 9/10)
__global__ __launch_bounds__(256) void outproj_mfma(
    const bf16* __restrict__ A, const bf16* __restrict__ Wt,
    const float* __restrict__ resid, float* __restrict__ out)
{
  __shared__ alignas(16) char SH[36864];
  bf16 (*T)[64][64] = reinterpret_cast<bf16(*)[64][64]>(SH);
  const int tid  = threadIdx.x;
  const int wave = tid >> 6, lane = tid & 63;
  const int l16 = lane & 15, quad = lane >> 4;
  const int wr = wave >> 1, wc = wave & 1;
  const int bx = blockIdx.x;
  const int c0 = (bx >> 7) * 128;     // 0..511
  const int g0 = (bx & 127) * 128;    // 0..16383

  const bf16* Bw = Wt + (size_t)5 * CCH * CCH + (size_t)c0 * CCH;

  f32x4 acc[4][4];
  #pragma unroll
  for (int rf = 0; rf < 4; rf++)
    #pragma unroll
    for (int cf = 0; cf < 4; cf++) acc[rf][cf] = (f32x4){0.f,0.f,0.f,0.f};

  const int lrow = lane >> 3, lcol = (lane & 7) * 8;
  const bf16* srcbase = (wave < 2)
      ? A  + ((size_t)g0 + wave * 64) * CCH
      : Bw + (size_t)((wave - 2) * 64) * CCH;

  for (int kt = 0; kt < 8; kt++){
    const int kc = kt * 64;
    #pragma unroll
    for (int c = 0; c < 8; c++){
      const bf16* g = srcbase + (size_t)(c * 8 + lrow) * CCH + kc + lcol;
      gload16(g, &T[wave][c * 8][0]);
    }
    __syncthreads();

    short8 af[4][2];
    #pragma unroll
    for (int rf = 0; rf < 4; rf++){
      af[rf][0] = *(const short8*)&T[wr][rf * 16 + l16][quad * 8];
      af[rf][1] = *(const short8*)&T[wr][rf * 16 + l16][32 + quad * 8];
    }
    #pragma unroll
    for (int cf = 0; cf < 4; cf++){
      const short8 b0 = *(const short8*)&T[2 + wc][cf * 16 + l16][quad * 8];
      const short8 b1 = *(const short8*)&T[2 + wc][cf * 16 + l16][32 + quad * 8];
      #pragma unroll
      for (int rf = 0; rf < 4; rf++){
        acc[rf][cf] = MFMA16(af[rf][0], b0, acc[rf][cf]);
        acc[rf][cf] = MFMA16(af[rf][1], b1, acc[rf][cf]);
      }
    }
    __syncthreads();
  }

  // -------- vectorized epilogue (per-wave region SH + wave*8704, f32[32][68])
  float (*Tf)[68] = reinterpret_cast<float(*)[68]>(SH + wave * 8704);
  const int cg = (lane & 15) * 4;     // float4-granular col within 64
  #pragma unroll
  for (int hf = 0; hf < 2; hf++){
    #pragma unroll
    for (int rf = 0; rf < 2; rf++)
      #pragma unroll
      for (int cf = 0; cf < 4; cf++)
        #pragma unroll
        for (int r = 0; r < 4; r++)
          Tf[rf * 16 + quad * 4 + r][cf * 16 + l16] = acc[hf * 2 + rf][cf][r];
    // intra-wave RAW through same pointer: compiler orders via lgkmcnt
    #pragma unroll
    for (int k = 0; k < 8; k++){
      const int row32 = k * 4 + quad;
      const size_t grow = (size_t)g0 + wr * 64 + hf * 32 + row32;
      const int gcol = c0 + wc * 64 + cg;
      float4 v  = *(const float4*)&Tf[row32][cg];
      float4 rz = *(const float4*)&resid[grow * CCH + gcol];
      v.x += rz.x; v.y += rz.y; v.z += rz.z; v.w += rz.w;
      *(float4*)&out[grow * CCH + gcol] = v;
    }
    if (hf == 0){
      // WAR: all hf=0 reads drained before hf=1 overwrites the same rows
      asm volatile("s_waitcnt lgkmcnt(0)" ::: "memory");
      __builtin_amdgcn_sched_barrier(0);
    }
  }
}

// --------------------------------------------------------------- launcher
extern "C" void kernel_launch(void* const* d_in, const int* in_sizes, int n_in,
                              void* d_out, int out_size, void* d_ws, size_t ws_size,
                              hipStream_t stream)
{
  const float* x     = (const float*)d_in[0];
  const float* txt   = (const float*)d_in[1];
  const int*   tmask = (const int*)d_in[2];
  const float* gqs   = (const float*)d_in[3];
  const float* gqb   = (const float*)d_in[4];
  const float* gks   = (const float*)d_in[5];
  const float* gkb   = (const float*)d_in[6];
  const float* gts   = (const float*)d_in[7];
  const float* gtb   = (const float*)d_in[8];
  const float* Wq    = (const float*)d_in[9];
  const float* Wks   = (const float*)d_in[10];
  const float* Wvs   = (const float*)d_in[11];
  const float* Wkc   = (const float*)d_in[12];
  const float* Wvc   = (const float*)d_in[13];
  const float* Wout  = (const float*)d_in[14];

  float* stats = (float*)d_ws;                            // 2048 floats (reserved)
  bf16* WtAll = (bf16*)(stats + 2048);                    // 6 * 512 * 512
  bf16* Xq  = WtAll + (size_t)6 * CCH * CCH;
  bf16* Xkv = Xq  + (size_t)BB * NN * CCH;                // now scratch
  bf16* Tn  = Xkv + (size_t)BB * NN * CCH;
  bf16* Qw  = Tn  + (size_t)BB * LPAD * CCH;
  bf16* Kw  = Qw  + (size_t)BB * NHH * NN * HDD;
  bf16* Vw  = Kw  + (size_t)BB * NHH * KVP * HDD;         // [b,h,hd,kvp]
  bf16* Aw  = Xq;                                         // attn output buffer

  // GroupNorm affine coeffs live in the (otherwise dead) Xkv region
  float* cAq = (float*)Xkv;                               // 16*512 each
  float* cBq = cAq + BB * CCH;
  float* cAk = cBq + BB * CCH;
  float* cBk = cAk + BB * CCH;

  pre_kernel<<<1408, 256, 0, stream>>>(
      x, txt, gqs, gqb, gks, gkb, gts, gtb,
      Wq, Wks, Wvs, Wkc, Wvc, Wout, WtAll,
      cAq, cBq, cAk, cBk, Tn);
  proj_all_mfma<<<1792, 256, 0, stream>>>(
      x, cAq, cBq, cAk, cBk, Tn, WtAll, Qw, Kw, Vw);
  attn_mfma_kernel<<<1024, 256, 0, stream>>>(Qw, Kw, Vw, tmask, Aw);
  outproj_mfma<<<512, 256, 0, stream>>>(Aw, WtAll, x, (float*)d_out);
}